// Round 2
// baseline (415.908 us; speedup 1.0000x reference)
//
#include <hip/hip_runtime.h>
#include <math.h>

#define NGRAPHS 64
#define NPER    2048
#define CDIM    512
#define KSEL    512
#define NNODES  (NGRAPHS * NPER)        // 131072
#define NSEL    (NGRAPHS * KSEL)        // 32768
#define OUT0    (NSEL * CDIM)           // 16777216

// ---------------- kernel 1: 1/||W|| ----------------
__global__ void norm_kernel(const float* __restrict__ W, float* __restrict__ invnorm) {
    __shared__ float red[512];
    int t = threadIdx.x;
    float w = W[t];
    red[t] = w * w;
    __syncthreads();
    for (int s = 256; s > 0; s >>= 1) {
        if (t < s) red[t] += red[t + s];
        __syncthreads();
    }
    if (t == 0) invnorm[0] = 1.0f / sqrtf(red[0]);
}

// ---------------- kernel 2: raw scores (wave per row) ----------------
__global__ void scores_kernel(const float* __restrict__ feat,
                              const float* __restrict__ W,
                              float* __restrict__ scores) {
    int gtid = blockIdx.x * blockDim.x + threadIdx.x;
    int row  = gtid >> 6;
    int lane = threadIdx.x & 63;
    if (row >= NNODES) return;
    const float4* rowp = (const float4*)(feat + (size_t)row * CDIM);
    const float4* Wp   = (const float4*)W;
    float acc = 0.f;
#pragma unroll
    for (int p = 0; p < 2; ++p) {
        float4 f = rowp[lane + 64 * p];
        float4 w = Wp[lane + 64 * p];
        acc += f.x * w.x + f.y * w.y + f.z * w.z + f.w * w.w;
    }
#pragma unroll
    for (int off = 32; off > 0; off >>= 1) acc += __shfl_down(acc, off);
    if (lane == 0) scores[row] = acc;   // division by ||W|| deferred (order-preserving)
}

// ---------------- kernel 3: per-graph top-k + index sort ----------------
// Bitonic compare-exchange pair: i = t + (t & ~(j-1)), partner p = i | j.
// Pure bit-ops (no integer div/mod — gfx950 has no v_div; avoids magic-mul VALU).
__global__ void __launch_bounds__(1024) topk_kernel(const float* __restrict__ scores,
                                                    int* __restrict__ flatidx,
                                                    float* __restrict__ idx_out) {
    __shared__ float s[NPER];
    __shared__ int   id[NPER];
    int b = blockIdx.x;
    int t = threadIdx.x;
    const float* sb = scores + b * NPER;
    for (int i = t; i < NPER; i += 1024) { s[i] = sb[i]; id[i] = i; }
    __syncthreads();

    // bitonic sort 2048 elements: score desc, index asc on ties
    // (matches jax top_k stability: equal scores -> lower index first)
    for (int k = 2; k <= NPER; k <<= 1) {
        for (int j = k >> 1; j > 0; j >>= 1) {
            int i = t + (t & ~(j - 1));   // (i & j) == 0
            int p = i | j;
            bool up = ((i & k) == 0);
            float si = s[i], sp = s[p];
            int   ii = id[i], ip = id[p];
            bool before = (si > sp) || (si == sp && ii < ip);
            if (up ? !before : before) {
                s[i] = sp; s[p] = si; id[i] = ip; id[p] = ii;
            }
            __syncthreads();
        }
    }

    // sort the selected 512 indices ascending (256 active compare pairs)
    for (int k = 2; k <= KSEL; k <<= 1) {
        for (int j = k >> 1; j > 0; j >>= 1) {
            if (t < KSEL / 2) {
                int i = t + (t & ~(j - 1));
                int p = i | j;
                bool up = ((i & k) == 0);
                int ii = id[i], ip = id[p];
                if (up ? (ii > ip) : (ii < ip)) { id[i] = ip; id[p] = ii; }
            }
            __syncthreads();
        }
    }

    if (t < KSEL) {
        int fi = b * NPER + id[t];
        flatidx[b * KSEL + t] = fi;
        idx_out[b * KSEL + t] = (float)fi;   // output 1 is compared as float values
    }
}

// ---------------- kernel 4: gather + sigmoid gate (wave per row) ----------------
__global__ void gather_kernel(const float* __restrict__ feat,
                              const float* __restrict__ scores,
                              const float* __restrict__ invnorm,
                              const int* __restrict__ flatidx,
                              float* __restrict__ out) {
    int gtid = blockIdx.x * blockDim.x + threadIdx.x;
    int row  = gtid >> 6;
    int lane = threadIdx.x & 63;
    if (row >= NSEL) return;
    int fi = flatidx[row];
    float y = scores[fi] * invnorm[0];
    float g = 1.0f / (1.0f + expf(-y));
    const float4* src = (const float4*)(feat + (size_t)fi * CDIM);
    float4*       dst = (float4*)(out + (size_t)row * CDIM);
#pragma unroll
    for (int p = 0; p < 2; ++p) {
        float4 f = src[lane + 64 * p];
        f.x *= g; f.y *= g; f.z *= g; f.w *= g;
        dst[lane + 64 * p] = f;
    }
}

extern "C" void kernel_launch(void* const* d_in, const int* in_sizes, int n_in,
                              void* d_out, int out_size, void* d_ws, size_t ws_size,
                              hipStream_t stream) {
    const float* feat = (const float*)d_in[0];
    const float* W    = (const float*)d_in[1];
    float* out     = (float*)d_out;
    float* idx_out = out + OUT0;

    float* ws      = (float*)d_ws;
    float* scores  = ws;                       // NNODES floats
    float* invnorm = ws + NNODES;              // 1 float (padded to 64)
    int*   flatidx = (int*)(ws + NNODES + 64); // NSEL ints

    norm_kernel  <<<1, 512, 0, stream>>>(W, invnorm);
    scores_kernel<<<NNODES / 4, 256, 0, stream>>>(feat, W, scores);
    topk_kernel  <<<NGRAPHS, 1024, 0, stream>>>(scores, flatidx, idx_out);
    gather_kernel<<<NSEL / 4, 256, 0, stream>>>(feat, scores, invnorm, flatidx, out);
}

// Round 3
// 402.544 us; speedup vs baseline: 1.0332x; 1.0332x over previous
//
#include <hip/hip_runtime.h>
#include <math.h>

#define NGRAPHS 64
#define NPER    2048
#define CDIM    512
#define KSEL    512
#define NNODES  (NGRAPHS * NPER)        // 131072
#define NSEL    (NGRAPHS * KSEL)        // 32768
#define OUT0    (NSEL * CDIM)           // 16777216

typedef float floatx4 __attribute__((ext_vector_type(4)));

// ---------------- kernel 1: normalized scores (wave per row, ||W|| fused) ----
__global__ void __launch_bounds__(1024) scores_kernel(const float* __restrict__ feat,
                                                      const float* __restrict__ W,
                                                      float* __restrict__ nscores) {
    int gtid = blockIdx.x * blockDim.x + threadIdx.x;
    int row  = gtid >> 6;                 // one wave per row; grid sized exactly
    int lane = threadIdx.x & 63;
    const float4* rowp = (const float4*)(feat + (size_t)row * CDIM);
    const float4* Wp   = (const float4*)W;
    float acc = 0.f, wss = 0.f;
#pragma unroll
    for (int p = 0; p < 2; ++p) {
        float4 f = rowp[lane + 64 * p];
        float4 w = Wp[lane + 64 * p];
        acc += f.x * w.x + f.y * w.y + f.z * w.z + f.w * w.w;
        wss += w.x * w.x + w.y * w.y + w.z * w.z + w.w * w.w;
    }
#pragma unroll
    for (int off = 32; off; off >>= 1) {
        acc += __shfl_down(acc, off);
        wss += __shfl_down(wss, off);
    }
    if (lane == 0) nscores[row] = acc / sqrtf(wss);
}

// ---------------- kernel 2: per-graph top-k via bitwise radix-select --------
// Each block (512 thr) owns one graph's 2048 scores, 4 per thread in registers.
// Find T = 512th-largest order-preserving key by binary search over 32 bits
// (count >= candidate each step), then compact selected indices in ascending
// index order via block prefix sums. Ties at T: lowest indices win (matches
// jax.lax.top_k stability).
__global__ void __launch_bounds__(512) topk_kernel(const float* __restrict__ nscores,
                                                   int* __restrict__ flatidx,
                                                   float* __restrict__ gate,
                                                   float* __restrict__ idx_out) {
    int b = blockIdx.x, t = threadIdx.x;
    int lane = t & 63, wid = t >> 6;      // 8 waves
    const float* sb = nscores + b * NPER;

    float sc[4]; unsigned key[4];
    float4 s4 = ((const float4*)sb)[t];   // elements t*4 .. t*4+3 (index order)
    sc[0] = s4.x; sc[1] = s4.y; sc[2] = s4.z; sc[3] = s4.w;
#pragma unroll
    for (int e = 0; e < 4; ++e) {
        unsigned u = __float_as_uint(sc[e]);
        key[e] = (u & 0x80000000u) ? ~u : (u | 0x80000000u);  // asc float -> asc uint
    }

    __shared__ unsigned wred[8];
    __shared__ unsigned bc;
    unsigned prefix = 0u;
    for (int bit = 31; bit >= 0; --bit) {
        unsigned cand = prefix | (1u << bit);
        int c = (key[0] >= cand) + (key[1] >= cand) + (key[2] >= cand) + (key[3] >= cand);
#pragma unroll
        for (int off = 32; off; off >>= 1) c += __shfl_down(c, off);
        if (lane == 0) wred[wid] = (unsigned)c;
        __syncthreads();
        if (t == 0) {
            unsigned tot = 0;
#pragma unroll
            for (int w = 0; w < 8; ++w) tot += wred[w];
            bc = tot;
        }
        __syncthreads();
        if (bc >= (unsigned)KSEL) prefix = cand;
        // safe: next wred write != bc address; next bc write is after a barrier
    }
    unsigned T = prefix;                  // exact 512th-largest key

    int gt[4], eq[4], cgt = 0, ceq = 0;
#pragma unroll
    for (int e = 0; e < 4; ++e) {
        gt[e] = key[e] > T; eq[e] = key[e] == T;
        cgt += gt[e]; ceq += eq[e];
    }
    // block exclusive scans (thread order == index order)
    int ig = cgt, ie = ceq;
#pragma unroll
    for (int off = 1; off < 64; off <<= 1) {
        int ng = __shfl_up(ig, off), ne = __shfl_up(ie, off);
        if (lane >= off) { ig += ng; ie += ne; }
    }
    __shared__ int wg[8], we[8], wgx[9], wex[9];
    if (lane == 63) { wg[wid] = ig; we[wid] = ie; }
    __syncthreads();
    if (t == 0) {
        int ag = 0, ae = 0;
        for (int w = 0; w < 8; ++w) { wgx[w] = ag; wex[w] = ae; ag += wg[w]; ae += we[w]; }
        wgx[8] = ag; wex[8] = ae;
    }
    __syncthreads();
    int base_gt = wgx[wid] + ig - cgt;    // exclusive prefix at this thread's elem 0
    int base_eq = wex[wid] + ie - ceq;
    int need = KSEL - wgx[8];             // how many ties to accept (lowest indices)

    int*   fo = flatidx + b * KSEL;
    float* io = idx_out + b * KSEL;
    float* go = gate    + b * KSEL;
#pragma unroll
    for (int e = 0; e < 4; ++e) {
        int i = t * 4 + e;
        bool sel = false; int pos = 0;
        if (gt[e]) { sel = true; pos = base_gt + (base_eq < need ? base_eq : need); }
        else if (eq[e] && base_eq < need) { sel = true; pos = base_gt + base_eq; }
        if (sel) {
            int fi = b * NPER + i;
            fo[pos] = fi;
            io[pos] = (float)fi;          // output 1 compared as float values
            go[pos] = 1.0f / (1.0f + expf(-sc[e]));
        }
        base_gt += gt[e]; base_eq += eq[e];
    }
}

// ---------------- kernel 3: gather + gate (wave per row, nt stores) ---------
__global__ void __launch_bounds__(1024) gather_kernel(const float* __restrict__ feat,
                                                      const float* __restrict__ gate,
                                                      const int* __restrict__ flatidx,
                                                      float* __restrict__ out) {
    int gtid = blockIdx.x * blockDim.x + threadIdx.x;
    int row  = gtid >> 6;
    int lane = threadIdx.x & 63;
    int   fi = flatidx[row];
    float g  = gate[row];
    const floatx4* src = (const floatx4*)(feat + (size_t)fi * CDIM);
    floatx4*       dst = (floatx4*)(out + (size_t)row * CDIM);
#pragma unroll
    for (int p = 0; p < 2; ++p) {
        floatx4 f = src[lane + 64 * p];
        f *= g;
        // nt store: don't evict feat from L3 (we want gather reads to hit L3)
        __builtin_nontemporal_store(f, &dst[lane + 64 * p]);
    }
}

extern "C" void kernel_launch(void* const* d_in, const int* in_sizes, int n_in,
                              void* d_out, int out_size, void* d_ws, size_t ws_size,
                              hipStream_t stream) {
    const float* feat = (const float*)d_in[0];
    const float* W    = (const float*)d_in[1];
    float* out     = (float*)d_out;
    float* idx_out = out + OUT0;

    float* ws      = (float*)d_ws;
    float* nscores = ws;                        // NNODES floats
    float* gate    = ws + NNODES;               // NSEL floats
    int*   flatidx = (int*)(ws + NNODES + NSEL);// NSEL ints

    scores_kernel<<<NNODES * 64 / 1024, 1024, 0, stream>>>(feat, W, nscores);
    topk_kernel  <<<NGRAPHS, 512, 0, stream>>>(nscores, flatidx, gate, idx_out);
    gather_kernel<<<NSEL * 64 / 1024, 1024, 0, stream>>>(feat, gate, flatidx, out);
}